// Round 8
// baseline (837.326 us; speedup 1.0000x reference)
//
#include <hip/hip_runtime.h>

// Problem constants: B=64, S=256, DIM=512, Q=8, K=1024
#define NROWS   16384
#define DIM     512
#define QQ      8
#define KK      1024
#define QOUT_SZ (NROWS * DIM)
#define IDX_SZ  (NROWS * QQ)
#define BK      64

// flag threshold: thr = FLAG_REL*||r|| + FLAG_ABS  (pairwise bf16-hh dist error
// sigma ~ 0.0045*||r||; 1024-trial worst ~0.015*||r||; 2.6x headroom)
#define FLAG_REL 0.04f
#define FLAG_ABS 0.02f

// rare rescan decomposition: 32 chunks/row x 32 codes/chunk, 8 lanes/code
#define RCH    32
#define RCODES (KK / RCH)

typedef __attribute__((ext_vector_type(8))) short short8x;   // 8 bf16 = 4 VGPR MFMA frag
typedef __attribute__((ext_vector_type(4))) float f32x4;     // MFMA acc

typedef __attribute__((address_space(3))) uint32_t lds_u32;
typedef __attribute__((address_space(1))) const uint32_t ga_u32;
#define GLOBAL_LOAD_LDS16(g, l) \
    __builtin_amdgcn_global_load_lds((ga_u32*)(g), (lds_u32*)(l), 16, 0, 0)

// ---------------- ws layout (~58 MB) ----------------
#define WS_LOSSP_OFF 0                                   // 1024 doubles (k_post grid)
#define WS_LOSSR_OFF (1024 * 8)                          // 1 double (rare-path loss)
#define WS_NFLAG_OFF (WS_LOSSR_OFF + 16)                 // 1 int (+pad)
#define WS_FLAG_OFF  (WS_NFLAG_OFF + 16)                 // NROWS int
#define WS_RNORM_OFF (WS_FLAG_OFF + NROWS * 4)           // NROWS float
#define WS_ENORM_OFF (WS_RNORM_OFF + NROWS * 4)          // QQ*KK float
#define WS_PD1_OFF   (WS_ENORM_OFF + QQ * KK * 4)        // 4*NROWS float
#define WS_PK1_OFF   (WS_PD1_OFF + 4 * NROWS * 4)        // 4*NROWS int
#define WS_PD2_OFF   (WS_PK1_OFF + 4 * NROWS * 4)        // 4*NROWS float
#define WS_PK2_OFF   (WS_PD2_OFF + 4 * NROWS * 4)        // 4*NROWS int
#define WS_PD3_OFF   (WS_PK2_OFF + 4 * NROWS * 4)        // 4*NROWS float
#define WS_EH_OFF    (WS_PD3_OFF + 4 * NROWS * 4)        // QQ*KK*DIM bf16
#define WS_XH_OFF    (WS_EH_OFF + (size_t)QQ * KK * DIM * 2)  // NROWS*DIM bf16
#define WS_RES_OFF   (WS_XH_OFF + (size_t)NROWS * DIM * 2)    // NROWS*DIM fp32
#define WS_PACK_OFF  (WS_RES_OFF + (size_t)NROWS * DIM * 4)   // NROWS u64 (rare argmin)

__device__ inline unsigned short bf16rne(float f) {
    unsigned int u = __float_as_uint(f);
    return (unsigned short)((u + 0x7FFFu + ((u >> 16) & 1u)) >> 16);
}

// merge two sorted (d1,k1,d2,k2,d3) triples -> mine
__device__ inline void merge3(float& d1, int& k1, float& d2, int& k2, float& d3,
                              float o1, int q1, float o2, int q2, float o3) {
    bool bf = (o1 < d1) || (o1 == d1 && q1 < k1);
    float n1d, n2d, n3d; int n1k, n2k;
    if (bf) {
        n1d = o1; n1k = q1;
        bool b2 = (o2 < d1) || (o2 == d1 && q2 < k1);
        if (b2) { n2d = o2; n2k = q2; n3d = fminf(o3, d1); }
        else    { n2d = d1; n2k = k1; n3d = fminf(o2, d2); }
    } else {
        n1d = d1; n1k = k1;
        bool a2 = (d2 < o1) || (d2 == o1 && k2 < q1);
        if (a2) { n2d = d2; n2k = k2; n3d = fminf(d3, o1); }
        else    { n2d = o1; n2k = q1; n3d = fminf(d2, o2); }
    }
    d1 = n1d; k1 = n1k; d2 = n2d; k2 = n2k; d3 = n3d;
}

// enorm over all QQ*KK embed rows (fp32 — same reduction as passing rounds)
__global__ __launch_bounds__(256) void k_enorm(const float4* __restrict__ e4,
                                               float* __restrict__ enorm) {
    int row  = blockIdx.x * 4 + (threadIdx.x >> 6);
    int lane = threadIdx.x & 63;
    float s = 0.f;
#pragma unroll
    for (int i = 0; i < 2; i++) {
        int c = lane + i * 64;
        float4 v = e4[row * (DIM / 4) + c];
        s += v.x * v.x + v.y * v.y + v.z * v.z + v.w * v.w;
    }
#pragma unroll
    for (int off = 32; off; off >>= 1) s += __shfl_down(s, off, 64);
    if (lane == 0) enorm[row] = s;
}

// res = x, rnorm = sum(x^2), Xh = bf16(x); block 0 zeroes loss_rare
__global__ __launch_bounds__(256) void k_prep(const float4* __restrict__ x4,
                                              float4* __restrict__ res4,
                                              float* __restrict__ rnorm,
                                              unsigned short* __restrict__ Xh,
                                              double* __restrict__ loss_rare) {
    if (blockIdx.x == 0 && threadIdx.x == 0) *loss_rare = 0.0;
    int row  = blockIdx.x * 4 + (threadIdx.x >> 6);
    int lane = threadIdx.x & 63;
    float s = 0.f;
#pragma unroll
    for (int i = 0; i < 2; i++) {
        int c = lane + i * 64;
        float4 v = x4[row * (DIM / 4) + c];
        res4[row * (DIM / 4) + c] = v;
        *(ushort4*)&Xh[(size_t)row * DIM + c * 4] =
            make_ushort4(bf16rne(v.x), bf16rne(v.y), bf16rne(v.z), bf16rne(v.w));
        s += v.x * v.x + v.y * v.y + v.z * v.z + v.w * v.w;
    }
#pragma unroll
    for (int off = 32; off; off >>= 1) s += __shfl_down(s, off, 64);
    if (lane == 0) rnorm[row] = s;
}

// cast ALL quantizer codebooks to bf16 once
__global__ __launch_bounds__(256) void k_ecast(const float4* __restrict__ e4,
                                               unsigned short* __restrict__ EhAll) {
    int i = blockIdx.x * 256 + threadIdx.x;
    float4 v = e4[i];
    *(ushort4*)&EhAll[(size_t)i * 4] =
        make_ushort4(bf16rne(v.x), bf16rne(v.y), bf16rne(v.z), bf16rne(v.w));
}

// ---- single-bf16 MFMA distance GEMM + per-row top-3 partials ----
// v6: 256x256 block tile, 1024 threads (16 waves, 8 wm x 2 wn). Per-wave inner
// loop and epilogue are IDENTICAL to the proven 128x256 kernel (32x128 wave
// tile, acc[2][8], same staging swizzle, same top-3); the block just aggregates
// 2x rows -> staged bytes/output 12->8 B, loads/wave 6->4, grid 256 = exactly
// 1 block/CU (no tail round). FETCH already L2-resident via XCD swizzle (R3/R4).
__global__ __launch_bounds__(1024, 4) void k_gemm(
        const unsigned short* __restrict__ Xh,
        const unsigned short* __restrict__ Eh,    // this quantizer
        const float* __restrict__ enorm_q,
        float* __restrict__ pd1, int* __restrict__ pk1,
        float* __restrict__ pd2, int* __restrict__ pk2,
        float* __restrict__ pd3, int* __restrict__ nflag) {
    __shared__ __align__(16) unsigned short sXh[256 * BK];   // 32 KB
    __shared__ __align__(16) unsigned short sEh[256 * BK];   // 32 KB
    __shared__ float sD1[2][256]; __shared__ int sK1[2][256];
    __shared__ float sD2[2][256]; __shared__ int sK2[2][256];
    __shared__ float sD3[2][256];

    const int tid = threadIdx.x;
    if (blockIdx.x == 0 && tid == 0) *nflag = 0;   // reset flag list for this step
    const int l   = tid & 63;
    const int w   = tid >> 6;          // 0..15
    const int wm  = w >> 1;            // 0..7  (32-row groups)
    const int wn  = w & 1;             // 0..1  (128-col groups)
    // XCD-aware bijective swizzle: all 4 nt-blocks of one mt share an XCD.
    // bid = ((mt>>3)*4 + nt)*8 + (mt&7); grid 256 = 64 mt x 4 nt.
    const int xcd = blockIdx.x & 7;
    const int tt  = blockIdx.x >> 3;
    const int nt  = tt & 3;
    const int mt  = ((tt >> 2) << 3) | xcd;   // 0..63
    const int l15 = l & 15;
    const int lq4 = l >> 4;
    const int srow = l >> 3;
    const int sgrp = (l & 7) ^ srow;

    f32x4 acc[2][8];
#pragma unroll
    for (int rt = 0; rt < 2; rt++)
#pragma unroll
        for (int ct = 0; ct < 8; ct++) acc[rt][ct] = (f32x4){0.f, 0.f, 0.f, 0.f};

    const unsigned short* gX = Xh + (size_t)(mt * 256) * DIM;
    const unsigned short* gE = Eh + (size_t)(nt * 256) * DIM;
    const int swz = l15 & 7;

    for (int c = 0; c < 8; c++) {
        __syncthreads();
#pragma unroll
        for (int i = 0; i < 2; i++) {
            int r = w * 16 + i * 8 + srow;
            GLOBAL_LOAD_LDS16(gX + (size_t)r * DIM + c * BK + sgrp * 8,
                              &sXh[(w * 16 + i * 8) * BK]);
        }
#pragma unroll
        for (int i = 0; i < 2; i++) {
            int r = w * 16 + i * 8 + srow;
            GLOBAL_LOAD_LDS16(gE + (size_t)r * DIM + c * BK + sgrp * 8,
                              &sEh[(w * 16 + i * 8) * BK]);
        }
        __syncthreads();

#pragma unroll
        for (int ks = 0; ks < 2; ks++) {
            const int g = ((ks * 4 + lq4) ^ swz) * 8;
            const int r0 = wm * 32 + l15;
            short8x a0 = *(const short8x*)&sXh[r0 * BK + g];
            short8x a1 = *(const short8x*)&sXh[(r0 + 16) * BK + g];
#pragma unroll
            for (int ct = 0; ct < 8; ct++) {
                const int br = wn * 128 + ct * 16 + l15;
                short8x b = *(const short8x*)&sEh[br * BK + g];
                acc[0][ct] = __builtin_amdgcn_mfma_f32_16x16x32_bf16(a0, b, acc[0][ct], 0, 0, 0);
                acc[1][ct] = __builtin_amdgcn_mfma_f32_16x16x32_bf16(a1, b, acc[1][ct], 0, 0, 0);
            }
        }
    }

    // epilogue: per-lane top-3 over this wave's 128 codes, per row slot
    float d1[2][4], d2[2][4], d3[2][4]; int k1[2][4], k2[2][4];
#pragma unroll
    for (int rt = 0; rt < 2; rt++)
#pragma unroll
        for (int r = 0; r < 4; r++) {
            d1[rt][r] = 3.4e38f; d2[rt][r] = 3.4e38f; d3[rt][r] = 3.4e38f;
            k1[rt][r] = 0; k2[rt][r] = 0;
        }

#pragma unroll
    for (int ct = 0; ct < 8; ct++) {
        int codeg = nt * 256 + wn * 128 + ct * 16 + l15;   // C/D: col = lane&15
        float en = enorm_q[codeg];
#pragma unroll
        for (int rt = 0; rt < 2; rt++)
#pragma unroll
            for (int r = 0; r < 4; r++) {
                float d = en - 2.0f * acc[rt][ct][r];
                if (d < d1[rt][r] || (d == d1[rt][r] && codeg < k1[rt][r])) {
                    d3[rt][r] = d2[rt][r];
                    d2[rt][r] = d1[rt][r]; k2[rt][r] = k1[rt][r];
                    d1[rt][r] = d; k1[rt][r] = codeg;
                } else if (d < d2[rt][r] || (d == d2[rt][r] && codeg < k2[rt][r])) {
                    d3[rt][r] = d2[rt][r];
                    d2[rt][r] = d; k2[rt][r] = codeg;
                } else {
                    d3[rt][r] = fminf(d3[rt][r], d);
                }
            }
    }
#pragma unroll
    for (int m = 1; m < 16; m <<= 1) {
#pragma unroll
        for (int rt = 0; rt < 2; rt++)
#pragma unroll
            for (int r = 0; r < 4; r++) {
                float o1 = __shfl_xor(d1[rt][r], m, 64);
                int   q1 = __shfl_xor(k1[rt][r], m, 64);
                float o2 = __shfl_xor(d2[rt][r], m, 64);
                int   q2 = __shfl_xor(k2[rt][r], m, 64);
                float o3 = __shfl_xor(d3[rt][r], m, 64);
                merge3(d1[rt][r], k1[rt][r], d2[rt][r], k2[rt][r], d3[rt][r],
                       o1, q1, o2, q2, o3);
            }
    }
    if (l15 == 0) {
#pragma unroll
        for (int rt = 0; rt < 2; rt++)
#pragma unroll
            for (int r = 0; r < 4; r++) {
                int rloc = wm * 32 + rt * 16 + lq4 * 4 + r;   // C/D: row = quad*4 + reg
                sD1[wn][rloc] = d1[rt][r]; sK1[wn][rloc] = k1[rt][r];
                sD2[wn][rloc] = d2[rt][r]; sK2[wn][rloc] = k2[rt][r];
                sD3[wn][rloc] = d3[rt][r];
            }
    }
    __syncthreads();
    if (tid < 256) {
        float a1 = sD1[0][tid], a2 = sD2[0][tid], a3 = sD3[0][tid];
        int   ak1 = sK1[0][tid], ak2 = sK2[0][tid];
        merge3(a1, ak1, a2, ak2, a3,
               sD1[1][tid], sK1[1][tid], sD2[1][tid], sK2[1][tid], sD3[1][tid]);
        int grow = mt * 256 + tid;
        pd1[nt * NROWS + grow] = a1; pk1[nt * NROWS + grow] = ak1;
        pd2[nt * NROWS + grow] = a2; pk2[nt * NROWS + grow] = ak2;
        pd3[nt * NROWS + grow] = a3;
    }
}

// fused combine + exact top-2 decision + residual update.
// 16 rows/block, 32 thr/row (grid 1024 -> 8192 waves); lane-striped float4
// access; e1/e2 kept in registers and selected for the update.
__global__ __launch_bounds__(512) void k_post(
        const float* __restrict__ pd1, const int* __restrict__ pk1,
        const float* __restrict__ pd2, const int* __restrict__ pk2,
        const float* __restrict__ pd3,
        float* __restrict__ res, float* __restrict__ rnorm,
        unsigned short* __restrict__ Xh,
        const float* __restrict__ embed_q, const float* __restrict__ enorm_q,
        double* __restrict__ loss_part, float* __restrict__ out_idx,
        int* __restrict__ nflag, int* __restrict__ flag_list,
        unsigned long long* __restrict__ packed, int q) {
    __shared__ int sIdx1[16], sIdx2[16], sFlag[16];
    __shared__ float ls_loss[8];

    const int tid = threadIdx.x;
    const int rbase = blockIdx.x * 16;

    // Phase A: combine 4 nt top-3 partials; flag rows with d3-d1 < thr
    if (tid < 16) {
        int row = rbase + tid;
        float d1 = pd1[row], d2 = pd2[row], d3 = pd3[row];
        int   k1 = pk1[row], k2 = pk2[row];
#pragma unroll
        for (int nt = 1; nt < 4; nt++) {
            merge3(d1, k1, d2, k2, d3,
                   pd1[nt * NROWS + row], pk1[nt * NROWS + row],
                   pd2[nt * NROWS + row], pk2[nt * NROWS + row],
                   pd3[nt * NROWS + row]);
        }
        sIdx1[tid] = k1; sIdx2[tid] = k2;
        float thr = FLAG_REL * sqrtf(rnorm[row]) + FLAG_ABS;
        int fl = (d3 - d1) < thr;
        sFlag[tid] = fl;
        if (fl) {
            int p = atomicAdd(nflag, 1);
            flag_list[p] = row;
            packed[p] = 0xFFFFFFFFFFFFFFFFull;   // init slot for k_rare1 atomicMin
        }
    }
    __syncthreads();

    // Phase B: exact fp32 dists of k1,k2 (32 thr/row), pick winner, update
    {
        const int rloc = tid >> 5, seg = tid & 31;
        const int row  = rbase + rloc;
        const int k1   = sIdx1[rloc], k2 = sIdx2[rloc];
        const int fl   = sFlag[rloc];
        const int wave = tid >> 6, lid = tid & 63;
        const float4* r4 = (const float4*)res + (size_t)row * (DIM / 4);
        const float4* a4 = (const float4*)embed_q + (size_t)k1 * (DIM / 4);
        const float4* b4 = (const float4*)embed_q + (size_t)k2 * (DIM / 4);
        float rn = rnorm[row];
        float4 rv[4], av[4], bv[4];
        float dot1 = 0.f, dot2 = 0.f;
#pragma unroll
        for (int u = 0; u < 4; u++) {
            rv[u] = r4[seg + 32 * u];
            av[u] = a4[seg + 32 * u];
            bv[u] = b4[seg + 32 * u];
            dot1 += rv[u].x * av[u].x; dot1 += rv[u].y * av[u].y;
            dot1 += rv[u].z * av[u].z; dot1 += rv[u].w * av[u].w;
            dot2 += rv[u].x * bv[u].x; dot2 += rv[u].y * bv[u].y;
            dot2 += rv[u].z * bv[u].z; dot2 += rv[u].w * bv[u].w;
        }
#pragma unroll
        for (int m = 1; m < 32; m <<= 1) {
            dot1 += __shfl_xor(dot1, m, 64);
            dot2 += __shfl_xor(dot2, m, 64);
        }
        float da = (rn + enorm_q[k1]) - 2.0f * dot1;
        float db = (rn + enorm_q[k2]) - 2.0f * dot2;
        int kw = (db < da || (db == da && k2 < k1)) ? k2 : k1;
        bool useb = (kw == k2);

        float sl = 0.f;
        if (!fl) {
            float sr = 0.f;
#pragma unroll
            for (int u = 0; u < 4; u++) {
                float4 ev = useb ? bv[u] : av[u];
                // t = q - r; q_st = r + t; new_r = r - q_st  (exact op order)
                float tx = ev.x - rv[u].x, ty = ev.y - rv[u].y;
                float tz = ev.z - rv[u].z, tw = ev.w - rv[u].w;
                float qx = rv[u].x + tx, qy = rv[u].y + ty;
                float qz = rv[u].z + tz, qw = rv[u].w + tw;
                float nx = rv[u].x - qx, ny = rv[u].y - qy;
                float nz = rv[u].z - qz, nw = rv[u].w - qw;
                int col = seg + 32 * u;
                ((float4*)res)[(size_t)row * (DIM / 4) + col] =
                    make_float4(nx, ny, nz, nw);
                *(ushort4*)&Xh[(size_t)row * DIM + col * 4] =
                    make_ushort4(bf16rne(nx), bf16rne(ny), bf16rne(nz), bf16rne(nw));
                sl += tx * tx + ty * ty + tz * tz + tw * tw;
                sr += nx * nx + ny * ny + nz * nz + nw * nw;
            }
            if (seg == 0) out_idx[(size_t)row * QQ + q] = (float)kw;
            float srr = sr;
#pragma unroll
            for (int m = 1; m < 32; m <<= 1) srr += __shfl_xor(srr, m, 64);
            if (seg == 0) rnorm[row] = srr;
        }
#pragma unroll
        for (int m = 1; m < 64; m <<= 1) sl += __shfl_xor(sl, m, 64);
        if (lid == 0) ls_loss[wave] = sl;
    }
    __syncthreads();
    if (tid == 0) {
        float s = 0.f;
#pragma unroll
        for (int w = 0; w < 8; w++) s += ls_loss[w];
        double cur = (q == 0) ? 0.0 : loss_part[blockIdx.x];
        loss_part[blockIdx.x] = cur + (double)s;
    }
}

// rare rescan phase 1: block = (flag-slot stream, chunk of 32 codes).
// 8 lanes/code x 64 dims; exact fp32 dist. Full in-block reduction of the 32
// candidates (wave shfl + LDS across waves) -> ONE atomicMin per block-iter.
// Packed u64 = (order-preserving dist | code) so min == (min dist, tie -> min
// code), matching jnp.argmin exactly.
__global__ __launch_bounds__(256) void k_rare1(
        const int* __restrict__ nflag, const int* __restrict__ flag_list,
        const float* __restrict__ res, const float* __restrict__ rnorm,
        const float* __restrict__ embed_q, const float* __restrict__ enorm_q,
        unsigned long long* __restrict__ packed) {
    __shared__ unsigned long long swmin[4];
    const int nf = *nflag;
    const int tid  = threadIdx.x;
    const int c    = blockIdx.x & (RCH - 1);          // chunk within codebook
    const int fs   = blockIdx.x >> 5;                 // starting flag slot
    const int fstp = (int)(gridDim.x >> 5);           // flag-slot stride
    const int code = c * RCODES + (tid >> 3);         // this thread's code
    const int seg  = tid & 7;                         // 64-dim segment
    const int lane = tid & 63, wv = tid >> 6;
    const float* ep = embed_q + (size_t)code * DIM + seg * 64;
    const float  en = enorm_q[code];
    for (int f = fs; f < nf; f += fstp) {
        const int row = flag_list[f];
        const float* rp = res + (size_t)row * DIM + seg * 64;
        float dot = 0.f;
#pragma unroll
        for (int u = 0; u < 16; u++) {
            float4 r = *(const float4*)(rp + u * 4);
            float4 e = *(const float4*)(ep + u * 4);
            dot += r.x * e.x; dot += r.y * e.y;
            dot += r.z * e.z; dot += r.w * e.w;
        }
#pragma unroll
        for (int m = 1; m < 8; m <<= 1) dot += __shfl_xor(dot, m, 64);
        unsigned long long pk = 0xFFFFFFFFFFFFFFFFull;
        if (seg == 0) {
            float dist = (rnorm[row] + en) - 2.0f * dot;
            unsigned int u = __float_as_uint(dist);
            u = (u & 0x80000000u) ? ~u : (u | 0x80000000u);
            pk = ((unsigned long long)u << 32) | (unsigned int)code;
        }
        // wave-level min over the 8 code-holders (lanes 0,8,...,56; rest = MAX)
#pragma unroll
        for (int m = 8; m < 64; m <<= 1) {
            unsigned int hi = (unsigned int)(pk >> 32), lo = (unsigned int)pk;
            unsigned int ohi = (unsigned int)__shfl_xor((int)hi, m, 64);
            unsigned int olo = (unsigned int)__shfl_xor((int)lo, m, 64);
            unsigned long long o = ((unsigned long long)ohi << 32) | olo;
            if (o < pk) pk = o;
        }
        if (lane == 0) swmin[wv] = pk;
        __syncthreads();
        if (tid == 0) {
            unsigned long long b = swmin[0];
            if (swmin[1] < b) b = swmin[1];
            if (swmin[2] < b) b = swmin[2];
            if (swmin[3] < b) b = swmin[3];
            atomicMin(&packed[f], b);
        }
        __syncthreads();
    }
}

// rare rescan phase 2: per flagged row, unpack winner + residual/Xh/loss update.
__global__ __launch_bounds__(128) void k_rare2(
        const int* __restrict__ nflag, const int* __restrict__ flag_list,
        const unsigned long long* __restrict__ packed,
        float* __restrict__ res, float* __restrict__ rnorm,
        unsigned short* __restrict__ Xh,
        const float* __restrict__ embed_q,
        double* __restrict__ loss_rare, float* __restrict__ out_idx, int q) {
    __shared__ float ls[2], rs[2];
    const int nf = *nflag;
    const int tid = threadIdx.x;
    const int lid = tid & 63, wv = tid >> 6;
    for (int f = blockIdx.x; f < nf; f += gridDim.x) {
        const int row   = flag_list[f];
        const int kbest = (int)(packed[f] & 0xFFFFFFFFull);
        float4 rv = *(const float4*)&res[(size_t)row * DIM + tid * 4];
        float4 ev = *(const float4*)&embed_q[(size_t)kbest * DIM + tid * 4];
        float tx = ev.x - rv.x, ty = ev.y - rv.y, tz = ev.z - rv.z, tw = ev.w - rv.w;
        float qx = rv.x + tx, qy = rv.y + ty, qz = rv.z + tz, qw = rv.w + tw;
        float nx = rv.x - qx, ny = rv.y - qy, nz = rv.z - qz, nw = rv.w - qw;
        *(float4*)&res[(size_t)row * DIM + tid * 4] = make_float4(nx, ny, nz, nw);
        *(ushort4*)&Xh[(size_t)row * DIM + tid * 4] =
            make_ushort4(bf16rne(nx), bf16rne(ny), bf16rne(nz), bf16rne(nw));
        float sl = tx * tx + ty * ty + tz * tz + tw * tw;
        float sr = nx * nx + ny * ny + nz * nz + nw * nw;
#pragma unroll
        for (int m = 1; m < 64; m <<= 1) {
            sl += __shfl_xor(sl, m, 64);
            sr += __shfl_xor(sr, m, 64);
        }
        if (lid == 0) { ls[wv] = sl; rs[wv] = sr; }
        __syncthreads();
        if (tid == 0) {
            rnorm[row] = rs[0] + rs[1];
            atomicAdd(loss_rare, (double)(ls[0] + ls[1]));
            out_idx[(size_t)row * QQ + q] = (float)kbest;
        }
        __syncthreads();
    }
}

// qout = x - res_final ; block 0 reduces loss partials + rare loss
__global__ __launch_bounds__(256) void k_final(const float4* __restrict__ x4,
                                               const float4* __restrict__ res4,
                                               float4* __restrict__ out4,
                                               const double* __restrict__ loss_part,
                                               const double* __restrict__ loss_rare,
                                               float* __restrict__ out_scalar) {
    int i = blockIdx.x * 256 + threadIdx.x;
    float4 a = x4[i], b = res4[i];
    out4[i] = make_float4(a.x - b.x, a.y - b.y, a.z - b.z, a.w - b.w);
    if (blockIdx.x == 0 && threadIdx.x < 64) {
        double s = 0.0;
#pragma unroll
        for (int j = 0; j < 16; j++) s += loss_part[threadIdx.x + 64 * j];
#pragma unroll
        for (int m = 1; m < 64; m <<= 1) s += __shfl_xor(s, m, 64);
        if (threadIdx.x == 0)
            out_scalar[0] = (float)((s + *loss_rare) * 2.0 / (double)QOUT_SZ);
    }
}

extern "C" void kernel_launch(void* const* d_in, const int* in_sizes, int n_in,
                              void* d_out, int out_size, void* d_ws, size_t ws_size,
                              hipStream_t stream) {
    const float* x      = (const float*)d_in[0];   // [NROWS][DIM]
    const float* embeds = (const float*)d_in[1];   // [QQ][KK][DIM]

    char*   ws        = (char*)d_ws;
    double* loss_part = (double*)(ws + WS_LOSSP_OFF);
    double* loss_rare = (double*)(ws + WS_LOSSR_OFF);
    int*    nflag     = (int*)   (ws + WS_NFLAG_OFF);
    int*    flag_list = (int*)   (ws + WS_FLAG_OFF);
    float*  rnorm     = (float*) (ws + WS_RNORM_OFF);
    float*  enorm     = (float*) (ws + WS_ENORM_OFF);
    float*  pd1       = (float*) (ws + WS_PD1_OFF);
    int*    pk1       = (int*)   (ws + WS_PK1_OFF);
    float*  pd2       = (float*) (ws + WS_PD2_OFF);
    int*    pk2       = (int*)   (ws + WS_PK2_OFF);
    float*  pd3       = (float*) (ws + WS_PD3_OFF);
    unsigned short* EhAll = (unsigned short*)(ws + WS_EH_OFF);
    unsigned short* Xh    = (unsigned short*)(ws + WS_XH_OFF);
    float*  res       = (float*) (ws + WS_RES_OFF);
    unsigned long long* packed = (unsigned long long*)(ws + WS_PACK_OFF);

    float* out_q      = (float*)d_out;
    float* out_idx    = out_q + QOUT_SZ;
    float* out_scalar = out_q + QOUT_SZ + IDX_SZ;

    k_enorm<<<(QQ * KK) / 4, 256, 0, stream>>>((const float4*)embeds, enorm);
    k_prep <<<NROWS / 4, 256, 0, stream>>>((const float4*)x, (float4*)res, rnorm, Xh, loss_rare);
    k_ecast<<<(QQ * KK * DIM) / 4 / 256, 256, 0, stream>>>((const float4*)embeds, EhAll);

    for (int q = 0; q < QQ; q++) {
        const float* embed_q = embeds + (size_t)q * KK * DIM;
        const float* enorm_q = enorm + q * KK;
        const unsigned short* Eh_q = EhAll + (size_t)q * KK * DIM;
        k_gemm<<<256, 1024, 0, stream>>>(Xh, Eh_q, enorm_q, pd1, pk1, pd2, pk2, pd3, nflag);
        k_post<<<1024, 512, 0, stream>>>(pd1, pk1, pd2, pk2, pd3, res, rnorm, Xh,
                                         embed_q, enorm_q, loss_part, out_idx,
                                         nflag, flag_list, packed, q);
        k_rare1<<<1024, 256, 0, stream>>>(nflag, flag_list, res, rnorm,
                                          embed_q, enorm_q, packed);
        k_rare2<<<128, 128, 0, stream>>>(nflag, flag_list, packed, res, rnorm, Xh,
                                         embed_q, loss_rare, out_idx, q);
    }

    k_final<<<QOUT_SZ / 4 / 256, 256, 0, stream>>>((const float4*)x, (const float4*)res,
                                                   (float4*)d_out, loss_part, loss_rare,
                                                   out_scalar);
}

// Round 9
// 779.261 us; speedup vs baseline: 1.0745x; 1.0745x over previous
//
#include <hip/hip_runtime.h>

// Problem constants: B=64, S=256, DIM=512, Q=8, K=1024
#define NROWS   16384
#define DIM     512
#define QQ      8
#define KK      1024
#define QOUT_SZ (NROWS * DIM)
#define IDX_SZ  (NROWS * QQ)
#define BK      64

// flag threshold: thr = FLAG_REL*||r|| + FLAG_ABS  (pairwise bf16-hh dist error
// sigma ~ 0.0045*||r||; 1024-trial worst ~0.015*||r||; 2.6x headroom)
#define FLAG_REL 0.04f
#define FLAG_ABS 0.02f

// rare rescan decomposition: 32 chunks/row x 32 codes/chunk, 8 lanes/code
#define RCH    32
#define RCODES (KK / RCH)

typedef __attribute__((ext_vector_type(8))) short short8x;   // 8 bf16 = 4 VGPR MFMA frag
typedef __attribute__((ext_vector_type(4))) float f32x4;     // MFMA acc

typedef __attribute__((address_space(3))) uint32_t lds_u32;
typedef __attribute__((address_space(1))) const uint32_t ga_u32;
#define GLOBAL_LOAD_LDS16(g, l) \
    __builtin_amdgcn_global_load_lds((ga_u32*)(g), (lds_u32*)(l), 16, 0, 0)

// ---------------- ws layout (~58 MB) ----------------
#define WS_LOSSP_OFF 0                                   // 1024 doubles (k_post grid)
#define WS_LOSSR_OFF (1024 * 8)                          // 1 double (rare-path loss)
#define WS_NFLAG_OFF (WS_LOSSR_OFF + 16)                 // 1 int (+pad)
#define WS_FLAG_OFF  (WS_NFLAG_OFF + 16)                 // NROWS int
#define WS_RNORM_OFF (WS_FLAG_OFF + NROWS * 4)           // NROWS float
#define WS_ENORM_OFF (WS_RNORM_OFF + NROWS * 4)          // QQ*KK float
#define WS_PD1_OFF   (WS_ENORM_OFF + QQ * KK * 4)        // 4*NROWS float
#define WS_PK1_OFF   (WS_PD1_OFF + 4 * NROWS * 4)        // 4*NROWS int
#define WS_PD2_OFF   (WS_PK1_OFF + 4 * NROWS * 4)        // 4*NROWS float
#define WS_PK2_OFF   (WS_PD2_OFF + 4 * NROWS * 4)        // 4*NROWS int
#define WS_PD3_OFF   (WS_PK2_OFF + 4 * NROWS * 4)        // 4*NROWS float
#define WS_EH_OFF    (WS_PD3_OFF + 4 * NROWS * 4)        // QQ*KK*DIM bf16
#define WS_XH_OFF    (WS_EH_OFF + (size_t)QQ * KK * DIM * 2)  // NROWS*DIM bf16
#define WS_RES_OFF   (WS_XH_OFF + (size_t)NROWS * DIM * 2)    // NROWS*DIM fp32
#define WS_PACK_OFF  (WS_RES_OFF + (size_t)NROWS * DIM * 4)   // NROWS u64 (rare argmin)

__device__ inline unsigned short bf16rne(float f) {
    unsigned int u = __float_as_uint(f);
    return (unsigned short)((u + 0x7FFFu + ((u >> 16) & 1u)) >> 16);
}

// merge two sorted (d1,k1,d2,k2,d3) triples -> mine
__device__ inline void merge3(float& d1, int& k1, float& d2, int& k2, float& d3,
                              float o1, int q1, float o2, int q2, float o3) {
    bool bf = (o1 < d1) || (o1 == d1 && q1 < k1);
    float n1d, n2d, n3d; int n1k, n2k;
    if (bf) {
        n1d = o1; n1k = q1;
        bool b2 = (o2 < d1) || (o2 == d1 && q2 < k1);
        if (b2) { n2d = o2; n2k = q2; n3d = fminf(o3, d1); }
        else    { n2d = d1; n2k = k1; n3d = fminf(o2, d2); }
    } else {
        n1d = d1; n1k = k1;
        bool a2 = (d2 < o1) || (d2 == o1 && k2 < q1);
        if (a2) { n2d = d2; n2k = k2; n3d = fminf(d3, o1); }
        else    { n2d = o1; n2k = q1; n3d = fminf(d2, o2); }
    }
    d1 = n1d; k1 = n1k; d2 = n2d; k2 = n2k; d3 = n3d;
}

// enorm over all QQ*KK embed rows (fp32 — same reduction as passing rounds)
__global__ __launch_bounds__(256) void k_enorm(const float4* __restrict__ e4,
                                               float* __restrict__ enorm) {
    int row  = blockIdx.x * 4 + (threadIdx.x >> 6);
    int lane = threadIdx.x & 63;
    float s = 0.f;
#pragma unroll
    for (int i = 0; i < 2; i++) {
        int c = lane + i * 64;
        float4 v = e4[row * (DIM / 4) + c];
        s += v.x * v.x + v.y * v.y + v.z * v.z + v.w * v.w;
    }
#pragma unroll
    for (int off = 32; off; off >>= 1) s += __shfl_down(s, off, 64);
    if (lane == 0) enorm[row] = s;
}

// res = x, rnorm = sum(x^2), Xh = bf16(x); block 0 zeroes loss_rare
__global__ __launch_bounds__(256) void k_prep(const float4* __restrict__ x4,
                                              float4* __restrict__ res4,
                                              float* __restrict__ rnorm,
                                              unsigned short* __restrict__ Xh,
                                              double* __restrict__ loss_rare) {
    if (blockIdx.x == 0 && threadIdx.x == 0) *loss_rare = 0.0;
    int row  = blockIdx.x * 4 + (threadIdx.x >> 6);
    int lane = threadIdx.x & 63;
    float s = 0.f;
#pragma unroll
    for (int i = 0; i < 2; i++) {
        int c = lane + i * 64;
        float4 v = x4[row * (DIM / 4) + c];
        res4[row * (DIM / 4) + c] = v;
        *(ushort4*)&Xh[(size_t)row * DIM + c * 4] =
            make_ushort4(bf16rne(v.x), bf16rne(v.y), bf16rne(v.z), bf16rne(v.w));
        s += v.x * v.x + v.y * v.y + v.z * v.z + v.w * v.w;
    }
#pragma unroll
    for (int off = 32; off; off >>= 1) s += __shfl_down(s, off, 64);
    if (lane == 0) rnorm[row] = s;
}

// cast ALL quantizer codebooks to bf16 once
__global__ __launch_bounds__(256) void k_ecast(const float4* __restrict__ e4,
                                               unsigned short* __restrict__ EhAll) {
    int i = blockIdx.x * 256 + threadIdx.x;
    float4 v = e4[i];
    *(ushort4*)&EhAll[(size_t)i * 4] =
        make_ushort4(bf16rne(v.x), bf16rne(v.y), bf16rne(v.z), bf16rne(v.w));
}

// ---- single-bf16 MFMA distance GEMM + per-row top-3 partials ----
// v7: back to the proven R7 geometry (128x256 tile, 512 thr, 2 blocks/CU,
// XCD swizzle). ONE change: the per-lane top-3 insert is branch-free
// (3 cmp + 7 cndmask). Valid because codeg strictly increases with ct within
// a lane, so tie -> keep-old == tie -> lower code. R8's 256^2 tile reverted
// (regressed 41.7->45.7us: epilogue work per output is constant and the
// 16-wave barrier + 1 block/CU lost the co-residency overlap).
__global__ __launch_bounds__(512, 4) void k_gemm(
        const unsigned short* __restrict__ Xh,
        const unsigned short* __restrict__ Eh,    // this quantizer
        const float* __restrict__ enorm_q,
        float* __restrict__ pd1, int* __restrict__ pk1,
        float* __restrict__ pd2, int* __restrict__ pk2,
        float* __restrict__ pd3, int* __restrict__ nflag) {
    __shared__ __align__(16) unsigned short sXh[128 * BK];   // 16 KB
    __shared__ __align__(16) unsigned short sEh[256 * BK];   // 32 KB
    __shared__ float sD1[2][128]; __shared__ int sK1[2][128];
    __shared__ float sD2[2][128]; __shared__ int sK2[2][128];
    __shared__ float sD3[2][128];

    const int tid = threadIdx.x;
    if (blockIdx.x == 0 && tid == 0) *nflag = 0;   // reset flag list for this step
    const int l   = tid & 63;
    const int w   = tid >> 6;
    const int wm  = w >> 1;
    const int wn  = w & 1;
    // XCD-aware bijective swizzle: all 4 nt-blocks of one mt share an XCD.
    const int xcd = blockIdx.x & 7;
    const int tt  = blockIdx.x >> 3;
    const int nt  = tt & 3;
    const int mt  = ((tt >> 2) << 3) | xcd;
    const int l15 = l & 15;
    const int lq4 = l >> 4;
    const int srow = l >> 3;
    const int sgrp = (l & 7) ^ srow;

    f32x4 acc[2][8];
#pragma unroll
    for (int rt = 0; rt < 2; rt++)
#pragma unroll
        for (int ct = 0; ct < 8; ct++) acc[rt][ct] = (f32x4){0.f, 0.f, 0.f, 0.f};

    const unsigned short* gX = Xh + (size_t)(mt * 128) * DIM;
    const unsigned short* gE = Eh + (size_t)(nt * 256) * DIM;
    const int swz = l15 & 7;

    for (int c = 0; c < 8; c++) {
        __syncthreads();
#pragma unroll
        for (int i = 0; i < 2; i++) {
            int r = w * 16 + i * 8 + srow;
            GLOBAL_LOAD_LDS16(gX + (size_t)r * DIM + c * BK + sgrp * 8,
                              &sXh[(w * 16 + i * 8) * BK]);
        }
#pragma unroll
        for (int i = 0; i < 4; i++) {
            int r = w * 32 + i * 8 + srow;
            GLOBAL_LOAD_LDS16(gE + (size_t)r * DIM + c * BK + sgrp * 8,
                              &sEh[(w * 32 + i * 8) * BK]);
        }
        __syncthreads();

#pragma unroll
        for (int ks = 0; ks < 2; ks++) {
            const int g = ((ks * 4 + lq4) ^ swz) * 8;
            const int r0 = wm * 32 + l15;
            short8x a0 = *(const short8x*)&sXh[r0 * BK + g];
            short8x a1 = *(const short8x*)&sXh[(r0 + 16) * BK + g];
#pragma unroll
            for (int ct = 0; ct < 8; ct++) {
                const int br = wn * 128 + ct * 16 + l15;
                short8x b = *(const short8x*)&sEh[br * BK + g];
                acc[0][ct] = __builtin_amdgcn_mfma_f32_16x16x32_bf16(a0, b, acc[0][ct], 0, 0, 0);
                acc[1][ct] = __builtin_amdgcn_mfma_f32_16x16x32_bf16(a1, b, acc[1][ct], 0, 0, 0);
            }
        }
    }

    // epilogue: per-lane top-3 over this wave's 128 codes, per row slot.
    // Branch-free insert: codes increase with ct, so a plain `<` implements
    // the tie->lower-code rule (on tie keep old). Semantics identical to the
    // sorted-insert chain, without divergence.
    float d1[2][4], d2[2][4], d3[2][4]; int k1[2][4], k2[2][4];
#pragma unroll
    for (int rt = 0; rt < 2; rt++)
#pragma unroll
        for (int r = 0; r < 4; r++) {
            d1[rt][r] = 3.4e38f; d2[rt][r] = 3.4e38f; d3[rt][r] = 3.4e38f;
            k1[rt][r] = 0; k2[rt][r] = 0;
        }

#pragma unroll
    for (int ct = 0; ct < 8; ct++) {
        int codeg = nt * 256 + wn * 128 + ct * 16 + l15;   // C/D: col = lane&15
        float en = enorm_q[codeg];
#pragma unroll
        for (int rt = 0; rt < 2; rt++)
#pragma unroll
            for (int r = 0; r < 4; r++) {
                float d = en - 2.0f * acc[rt][ct][r];
                bool b1 = d < d1[rt][r];
                bool b2 = d < d2[rt][r];
                bool b3 = d < d3[rt][r];
                d3[rt][r] = b2 ? d2[rt][r] : (b3 ? d : d3[rt][r]);
                d2[rt][r] = b1 ? d1[rt][r] : (b2 ? d : d2[rt][r]);
                k2[rt][r] = b1 ? k1[rt][r] : (b2 ? codeg : k2[rt][r]);
                d1[rt][r] = b1 ? d : d1[rt][r];
                k1[rt][r] = b1 ? codeg : k1[rt][r];
            }
    }
#pragma unroll
    for (int m = 1; m < 16; m <<= 1) {
#pragma unroll
        for (int rt = 0; rt < 2; rt++)
#pragma unroll
            for (int r = 0; r < 4; r++) {
                float o1 = __shfl_xor(d1[rt][r], m, 64);
                int   q1 = __shfl_xor(k1[rt][r], m, 64);
                float o2 = __shfl_xor(d2[rt][r], m, 64);
                int   q2 = __shfl_xor(k2[rt][r], m, 64);
                float o3 = __shfl_xor(d3[rt][r], m, 64);
                merge3(d1[rt][r], k1[rt][r], d2[rt][r], k2[rt][r], d3[rt][r],
                       o1, q1, o2, q2, o3);
            }
    }
    if (l15 == 0) {
#pragma unroll
        for (int rt = 0; rt < 2; rt++)
#pragma unroll
            for (int r = 0; r < 4; r++) {
                int rloc = wm * 32 + rt * 16 + lq4 * 4 + r;   // C/D: row = quad*4 + reg
                sD1[wn][rloc] = d1[rt][r]; sK1[wn][rloc] = k1[rt][r];
                sD2[wn][rloc] = d2[rt][r]; sK2[wn][rloc] = k2[rt][r];
                sD3[wn][rloc] = d3[rt][r];
            }
    }
    __syncthreads();
    if (tid < 128) {
        float a1 = sD1[0][tid], a2 = sD2[0][tid], a3 = sD3[0][tid];
        int   ak1 = sK1[0][tid], ak2 = sK2[0][tid];
        merge3(a1, ak1, a2, ak2, a3,
               sD1[1][tid], sK1[1][tid], sD2[1][tid], sK2[1][tid], sD3[1][tid]);
        int grow = mt * 128 + tid;
        pd1[nt * NROWS + grow] = a1; pk1[nt * NROWS + grow] = ak1;
        pd2[nt * NROWS + grow] = a2; pk2[nt * NROWS + grow] = ak2;
        pd3[nt * NROWS + grow] = a3;
    }
}

// fused combine + exact top-2 decision + residual update.
// 16 rows/block, 32 thr/row (grid 1024 -> 8192 waves); lane-striped float4
// access; e1/e2 kept in registers and selected for the update.
__global__ __launch_bounds__(512) void k_post(
        const float* __restrict__ pd1, const int* __restrict__ pk1,
        const float* __restrict__ pd2, const int* __restrict__ pk2,
        const float* __restrict__ pd3,
        float* __restrict__ res, float* __restrict__ rnorm,
        unsigned short* __restrict__ Xh,
        const float* __restrict__ embed_q, const float* __restrict__ enorm_q,
        double* __restrict__ loss_part, float* __restrict__ out_idx,
        int* __restrict__ nflag, int* __restrict__ flag_list,
        unsigned long long* __restrict__ packed, int q) {
    __shared__ int sIdx1[16], sIdx2[16], sFlag[16];
    __shared__ float ls_loss[8];

    const int tid = threadIdx.x;
    const int rbase = blockIdx.x * 16;

    // Phase A: combine 4 nt top-3 partials; flag rows with d3-d1 < thr
    if (tid < 16) {
        int row = rbase + tid;
        float d1 = pd1[row], d2 = pd2[row], d3 = pd3[row];
        int   k1 = pk1[row], k2 = pk2[row];
#pragma unroll
        for (int nt = 1; nt < 4; nt++) {
            merge3(d1, k1, d2, k2, d3,
                   pd1[nt * NROWS + row], pk1[nt * NROWS + row],
                   pd2[nt * NROWS + row], pk2[nt * NROWS + row],
                   pd3[nt * NROWS + row]);
        }
        sIdx1[tid] = k1; sIdx2[tid] = k2;
        float thr = FLAG_REL * sqrtf(rnorm[row]) + FLAG_ABS;
        int fl = (d3 - d1) < thr;
        sFlag[tid] = fl;
        if (fl) {
            int p = atomicAdd(nflag, 1);
            flag_list[p] = row;
            packed[p] = 0xFFFFFFFFFFFFFFFFull;   // init slot for k_rare1 atomicMin
        }
    }
    __syncthreads();

    // Phase B: exact fp32 dists of k1,k2 (32 thr/row), pick winner, update
    {
        const int rloc = tid >> 5, seg = tid & 31;
        const int row  = rbase + rloc;
        const int k1   = sIdx1[rloc], k2 = sIdx2[rloc];
        const int fl   = sFlag[rloc];
        const int wave = tid >> 6, lid = tid & 63;
        const float4* r4 = (const float4*)res + (size_t)row * (DIM / 4);
        const float4* a4 = (const float4*)embed_q + (size_t)k1 * (DIM / 4);
        const float4* b4 = (const float4*)embed_q + (size_t)k2 * (DIM / 4);
        float rn = rnorm[row];
        float4 rv[4], av[4], bv[4];
        float dot1 = 0.f, dot2 = 0.f;
#pragma unroll
        for (int u = 0; u < 4; u++) {
            rv[u] = r4[seg + 32 * u];
            av[u] = a4[seg + 32 * u];
            bv[u] = b4[seg + 32 * u];
            dot1 += rv[u].x * av[u].x; dot1 += rv[u].y * av[u].y;
            dot1 += rv[u].z * av[u].z; dot1 += rv[u].w * av[u].w;
            dot2 += rv[u].x * bv[u].x; dot2 += rv[u].y * bv[u].y;
            dot2 += rv[u].z * bv[u].z; dot2 += rv[u].w * bv[u].w;
        }
#pragma unroll
        for (int m = 1; m < 32; m <<= 1) {
            dot1 += __shfl_xor(dot1, m, 64);
            dot2 += __shfl_xor(dot2, m, 64);
        }
        float da = (rn + enorm_q[k1]) - 2.0f * dot1;
        float db = (rn + enorm_q[k2]) - 2.0f * dot2;
        int kw = (db < da || (db == da && k2 < k1)) ? k2 : k1;
        bool useb = (kw == k2);

        float sl = 0.f;
        if (!fl) {
            float sr = 0.f;
#pragma unroll
            for (int u = 0; u < 4; u++) {
                float4 ev = useb ? bv[u] : av[u];
                // t = q - r; q_st = r + t; new_r = r - q_st  (exact op order)
                float tx = ev.x - rv[u].x, ty = ev.y - rv[u].y;
                float tz = ev.z - rv[u].z, tw = ev.w - rv[u].w;
                float qx = rv[u].x + tx, qy = rv[u].y + ty;
                float qz = rv[u].z + tz, qw = rv[u].w + tw;
                float nx = rv[u].x - qx, ny = rv[u].y - qy;
                float nz = rv[u].z - qz, nw = rv[u].w - qw;
                int col = seg + 32 * u;
                ((float4*)res)[(size_t)row * (DIM / 4) + col] =
                    make_float4(nx, ny, nz, nw);
                *(ushort4*)&Xh[(size_t)row * DIM + col * 4] =
                    make_ushort4(bf16rne(nx), bf16rne(ny), bf16rne(nz), bf16rne(nw));
                sl += tx * tx + ty * ty + tz * tz + tw * tw;
                sr += nx * nx + ny * ny + nz * nz + nw * nw;
            }
            if (seg == 0) out_idx[(size_t)row * QQ + q] = (float)kw;
            float srr = sr;
#pragma unroll
            for (int m = 1; m < 32; m <<= 1) srr += __shfl_xor(srr, m, 64);
            if (seg == 0) rnorm[row] = srr;
        }
#pragma unroll
        for (int m = 1; m < 64; m <<= 1) sl += __shfl_xor(sl, m, 64);
        if (lid == 0) ls_loss[wave] = sl;
    }
    __syncthreads();
    if (tid == 0) {
        float s = 0.f;
#pragma unroll
        for (int w = 0; w < 8; w++) s += ls_loss[w];
        double cur = (q == 0) ? 0.0 : loss_part[blockIdx.x];
        loss_part[blockIdx.x] = cur + (double)s;
    }
}

// rare rescan phase 1: block = (flag-slot stream, chunk of 32 codes).
// 8 lanes/code x 64 dims; exact fp32 dist. Full in-block reduction of the 32
// candidates (wave shfl + LDS across waves) -> ONE atomicMin per block-iter.
// Packed u64 = (order-preserving dist | code) so min == (min dist, tie -> min
// code), matching jnp.argmin exactly.
__global__ __launch_bounds__(256) void k_rare1(
        const int* __restrict__ nflag, const int* __restrict__ flag_list,
        const float* __restrict__ res, const float* __restrict__ rnorm,
        const float* __restrict__ embed_q, const float* __restrict__ enorm_q,
        unsigned long long* __restrict__ packed) {
    __shared__ unsigned long long swmin[4];
    const int nf = *nflag;
    const int tid  = threadIdx.x;
    const int c    = blockIdx.x & (RCH - 1);          // chunk within codebook
    const int fs   = blockIdx.x >> 5;                 // starting flag slot
    const int fstp = (int)(gridDim.x >> 5);           // flag-slot stride
    const int code = c * RCODES + (tid >> 3);         // this thread's code
    const int seg  = tid & 7;                         // 64-dim segment
    const int lane = tid & 63, wv = tid >> 6;
    const float* ep = embed_q + (size_t)code * DIM + seg * 64;
    const float  en = enorm_q[code];
    for (int f = fs; f < nf; f += fstp) {
        const int row = flag_list[f];
        const float* rp = res + (size_t)row * DIM + seg * 64;
        float dot = 0.f;
#pragma unroll
        for (int u = 0; u < 16; u++) {
            float4 r = *(const float4*)(rp + u * 4);
            float4 e = *(const float4*)(ep + u * 4);
            dot += r.x * e.x; dot += r.y * e.y;
            dot += r.z * e.z; dot += r.w * e.w;
        }
#pragma unroll
        for (int m = 1; m < 8; m <<= 1) dot += __shfl_xor(dot, m, 64);
        unsigned long long pk = 0xFFFFFFFFFFFFFFFFull;
        if (seg == 0) {
            float dist = (rnorm[row] + en) - 2.0f * dot;
            unsigned int u = __float_as_uint(dist);
            u = (u & 0x80000000u) ? ~u : (u | 0x80000000u);
            pk = ((unsigned long long)u << 32) | (unsigned int)code;
        }
        // wave-level min over the 8 code-holders (lanes 0,8,...,56; rest = MAX)
#pragma unroll
        for (int m = 8; m < 64; m <<= 1) {
            unsigned int hi = (unsigned int)(pk >> 32), lo = (unsigned int)pk;
            unsigned int ohi = (unsigned int)__shfl_xor((int)hi, m, 64);
            unsigned int olo = (unsigned int)__shfl_xor((int)lo, m, 64);
            unsigned long long o = ((unsigned long long)ohi << 32) | olo;
            if (o < pk) pk = o;
        }
        if (lane == 0) swmin[wv] = pk;
        __syncthreads();
        if (tid == 0) {
            unsigned long long b = swmin[0];
            if (swmin[1] < b) b = swmin[1];
            if (swmin[2] < b) b = swmin[2];
            if (swmin[3] < b) b = swmin[3];
            atomicMin(&packed[f], b);
        }
        __syncthreads();
    }
}

// rare rescan phase 2: per flagged row, unpack winner + residual/Xh/loss update.
__global__ __launch_bounds__(128) void k_rare2(
        const int* __restrict__ nflag, const int* __restrict__ flag_list,
        const unsigned long long* __restrict__ packed,
        float* __restrict__ res, float* __restrict__ rnorm,
        unsigned short* __restrict__ Xh,
        const float* __restrict__ embed_q,
        double* __restrict__ loss_rare, float* __restrict__ out_idx, int q) {
    __shared__ float ls[2], rs[2];
    const int nf = *nflag;
    const int tid = threadIdx.x;
    const int lid = tid & 63, wv = tid >> 6;
    for (int f = blockIdx.x; f < nf; f += gridDim.x) {
        const int row   = flag_list[f];
        const int kbest = (int)(packed[f] & 0xFFFFFFFFull);
        float4 rv = *(const float4*)&res[(size_t)row * DIM + tid * 4];
        float4 ev = *(const float4*)&embed_q[(size_t)kbest * DIM + tid * 4];
        float tx = ev.x - rv.x, ty = ev.y - rv.y, tz = ev.z - rv.z, tw = ev.w - rv.w;
        float qx = rv.x + tx, qy = rv.y + ty, qz = rv.z + tz, qw = rv.w + tw;
        float nx = rv.x - qx, ny = rv.y - qy, nz = rv.z - qz, nw = rv.w - qw;
        *(float4*)&res[(size_t)row * DIM + tid * 4] = make_float4(nx, ny, nz, nw);
        *(ushort4*)&Xh[(size_t)row * DIM + tid * 4] =
            make_ushort4(bf16rne(nx), bf16rne(ny), bf16rne(nz), bf16rne(nw));
        float sl = tx * tx + ty * ty + tz * tz + tw * tw;
        float sr = nx * nx + ny * ny + nz * nz + nw * nw;
#pragma unroll
        for (int m = 1; m < 64; m <<= 1) {
            sl += __shfl_xor(sl, m, 64);
            sr += __shfl_xor(sr, m, 64);
        }
        if (lid == 0) { ls[wv] = sl; rs[wv] = sr; }
        __syncthreads();
        if (tid == 0) {
            rnorm[row] = rs[0] + rs[1];
            atomicAdd(loss_rare, (double)(ls[0] + ls[1]));
            out_idx[(size_t)row * QQ + q] = (float)kbest;
        }
        __syncthreads();
    }
}

// qout = x - res_final ; block 0 reduces loss partials + rare loss
__global__ __launch_bounds__(256) void k_final(const float4* __restrict__ x4,
                                               const float4* __restrict__ res4,
                                               float4* __restrict__ out4,
                                               const double* __restrict__ loss_part,
                                               const double* __restrict__ loss_rare,
                                               float* __restrict__ out_scalar) {
    int i = blockIdx.x * 256 + threadIdx.x;
    float4 a = x4[i], b = res4[i];
    out4[i] = make_float4(a.x - b.x, a.y - b.y, a.z - b.z, a.w - b.w);
    if (blockIdx.x == 0 && threadIdx.x < 64) {
        double s = 0.0;
#pragma unroll
        for (int j = 0; j < 16; j++) s += loss_part[threadIdx.x + 64 * j];
#pragma unroll
        for (int m = 1; m < 64; m <<= 1) s += __shfl_xor(s, m, 64);
        if (threadIdx.x == 0)
            out_scalar[0] = (float)((s + *loss_rare) * 2.0 / (double)QOUT_SZ);
    }
}

extern "C" void kernel_launch(void* const* d_in, const int* in_sizes, int n_in,
                              void* d_out, int out_size, void* d_ws, size_t ws_size,
                              hipStream_t stream) {
    const float* x      = (const float*)d_in[0];   // [NROWS][DIM]
    const float* embeds = (const float*)d_in[1];   // [QQ][KK][DIM]

    char*   ws        = (char*)d_ws;
    double* loss_part = (double*)(ws + WS_LOSSP_OFF);
    double* loss_rare = (double*)(ws + WS_LOSSR_OFF);
    int*    nflag     = (int*)   (ws + WS_NFLAG_OFF);
    int*    flag_list = (int*)   (ws + WS_FLAG_OFF);
    float*  rnorm     = (float*) (ws + WS_RNORM_OFF);
    float*  enorm     = (float*) (ws + WS_ENORM_OFF);
    float*  pd1       = (float*) (ws + WS_PD1_OFF);
    int*    pk1       = (int*)   (ws + WS_PK1_OFF);
    float*  pd2       = (float*) (ws + WS_PD2_OFF);
    int*    pk2       = (int*)   (ws + WS_PK2_OFF);
    float*  pd3       = (float*) (ws + WS_PD3_OFF);
    unsigned short* EhAll = (unsigned short*)(ws + WS_EH_OFF);
    unsigned short* Xh    = (unsigned short*)(ws + WS_XH_OFF);
    float*  res       = (float*) (ws + WS_RES_OFF);
    unsigned long long* packed = (unsigned long long*)(ws + WS_PACK_OFF);

    float* out_q      = (float*)d_out;
    float* out_idx    = out_q + QOUT_SZ;
    float* out_scalar = out_q + QOUT_SZ + IDX_SZ;

    k_enorm<<<(QQ * KK) / 4, 256, 0, stream>>>((const float4*)embeds, enorm);
    k_prep <<<NROWS / 4, 256, 0, stream>>>((const float4*)x, (float4*)res, rnorm, Xh, loss_rare);
    k_ecast<<<(QQ * KK * DIM) / 4 / 256, 256, 0, stream>>>((const float4*)embeds, EhAll);

    for (int q = 0; q < QQ; q++) {
        const float* embed_q = embeds + (size_t)q * KK * DIM;
        const float* enorm_q = enorm + q * KK;
        const unsigned short* Eh_q = EhAll + (size_t)q * KK * DIM;
        k_gemm<<<512, 512, 0, stream>>>(Xh, Eh_q, enorm_q, pd1, pk1, pd2, pk2, pd3, nflag);
        k_post<<<1024, 512, 0, stream>>>(pd1, pk1, pd2, pk2, pd3, res, rnorm, Xh,
                                         embed_q, enorm_q, loss_part, out_idx,
                                         nflag, flag_list, packed, q);
        k_rare1<<<1024, 256, 0, stream>>>(nflag, flag_list, res, rnorm,
                                          embed_q, enorm_q, packed);
        k_rare2<<<128, 128, 0, stream>>>(nflag, flag_list, packed, res, rnorm, Xh,
                                         embed_q, loss_rare, out_idx, q);
    }

    k_final<<<QOUT_SZ / 4 / 256, 256, 0, stream>>>((const float4*)x, (const float4*)res,
                                                   (float4*)d_out, loss_part, loss_rare,
                                                   out_scalar);
}

// Round 10
// 763.881 us; speedup vs baseline: 1.0961x; 1.0201x over previous
//
#include <hip/hip_runtime.h>

// Problem constants: B=64, S=256, DIM=512, Q=8, K=1024
#define NROWS   16384
#define DIM     512
#define QQ      8
#define KK      1024
#define QOUT_SZ (NROWS * DIM)
#define IDX_SZ  (NROWS * QQ)
#define BK      64

// flag threshold: thr = FLAG_REL*||r|| + FLAG_ABS  (pairwise bf16-hh dist error
// sigma ~ 0.0045*||r||; 1024-trial worst ~0.015*||r||; 2.6x headroom)
#define FLAG_REL 0.04f
#define FLAG_ABS 0.02f

// rare rescan decomposition: 32 chunks/row x 32 codes/chunk, 8 lanes/code
#define RCH    32
#define RCODES (KK / RCH)

typedef __attribute__((ext_vector_type(8))) short short8x;   // 8 bf16 = 4 VGPR MFMA frag
typedef __attribute__((ext_vector_type(4))) float f32x4;     // MFMA acc

typedef __attribute__((address_space(3))) uint32_t lds_u32;
typedef __attribute__((address_space(1))) const uint32_t ga_u32;
#define GLOBAL_LOAD_LDS16(g, l) \
    __builtin_amdgcn_global_load_lds((ga_u32*)(g), (lds_u32*)(l), 16, 0, 0)

// ---------------- ws layout (~58 MB) ----------------
#define WS_LOSSP_OFF 0                                   // 1024 doubles (k_post grid)
#define WS_LOSSR_OFF (1024 * 8)                          // 1 double (rare-path loss)
#define WS_NFLAG_OFF (WS_LOSSR_OFF + 16)                 // 1 int (+pad)
#define WS_FLAG_OFF  (WS_NFLAG_OFF + 16)                 // NROWS int
#define WS_RNORM_OFF (WS_FLAG_OFF + NROWS * 4)           // NROWS float
#define WS_ENORM_OFF (WS_RNORM_OFF + NROWS * 4)          // QQ*KK float
#define WS_PD1_OFF   (WS_ENORM_OFF + QQ * KK * 4)        // 4*NROWS float
#define WS_PK1_OFF   (WS_PD1_OFF + 4 * NROWS * 4)        // 4*NROWS int
#define WS_PD2_OFF   (WS_PK1_OFF + 4 * NROWS * 4)        // 4*NROWS float
#define WS_PK2_OFF   (WS_PD2_OFF + 4 * NROWS * 4)        // 4*NROWS int
#define WS_PD3_OFF   (WS_PK2_OFF + 4 * NROWS * 4)        // 4*NROWS float
#define WS_EH_OFF    (WS_PD3_OFF + 4 * NROWS * 4)        // QQ*KK*DIM bf16
#define WS_XH_OFF    (WS_EH_OFF + (size_t)QQ * KK * DIM * 2)  // NROWS*DIM bf16
#define WS_RES_OFF   (WS_XH_OFF + (size_t)NROWS * DIM * 2)    // NROWS*DIM fp32
#define WS_PACK_OFF  (WS_RES_OFF + (size_t)NROWS * DIM * 4)   // NROWS u64 (rare argmin)

__device__ inline unsigned short bf16rne(float f) {
    unsigned int u = __float_as_uint(f);
    return (unsigned short)((u + 0x7FFFu + ((u >> 16) & 1u)) >> 16);
}

// merge two sorted (d1,k1,d2,k2,d3) triples -> mine
__device__ inline void merge3(float& d1, int& k1, float& d2, int& k2, float& d3,
                              float o1, int q1, float o2, int q2, float o3) {
    bool bf = (o1 < d1) || (o1 == d1 && q1 < k1);
    float n1d, n2d, n3d; int n1k, n2k;
    if (bf) {
        n1d = o1; n1k = q1;
        bool b2 = (o2 < d1) || (o2 == d1 && q2 < k1);
        if (b2) { n2d = o2; n2k = q2; n3d = fminf(o3, d1); }
        else    { n2d = d1; n2k = k1; n3d = fminf(o2, d2); }
    } else {
        n1d = d1; n1k = k1;
        bool a2 = (d2 < o1) || (d2 == o1 && k2 < q1);
        if (a2) { n2d = d2; n2k = k2; n3d = fminf(d3, o1); }
        else    { n2d = o1; n2k = q1; n3d = fminf(d2, o2); }
    }
    d1 = n1d; k1 = n1k; d2 = n2d; k2 = n2k; d3 = n3d;
}

// enorm over all QQ*KK embed rows (fp32 — same reduction as passing rounds)
__global__ __launch_bounds__(256) void k_enorm(const float4* __restrict__ e4,
                                               float* __restrict__ enorm) {
    int row  = blockIdx.x * 4 + (threadIdx.x >> 6);
    int lane = threadIdx.x & 63;
    float s = 0.f;
#pragma unroll
    for (int i = 0; i < 2; i++) {
        int c = lane + i * 64;
        float4 v = e4[row * (DIM / 4) + c];
        s += v.x * v.x + v.y * v.y + v.z * v.z + v.w * v.w;
    }
#pragma unroll
    for (int off = 32; off; off >>= 1) s += __shfl_down(s, off, 64);
    if (lane == 0) enorm[row] = s;
}

// res = x, rnorm = sum(x^2), Xh = bf16(x); block 0 zeroes loss_rare
__global__ __launch_bounds__(256) void k_prep(const float4* __restrict__ x4,
                                              float4* __restrict__ res4,
                                              float* __restrict__ rnorm,
                                              unsigned short* __restrict__ Xh,
                                              double* __restrict__ loss_rare) {
    if (blockIdx.x == 0 && threadIdx.x == 0) *loss_rare = 0.0;
    int row  = blockIdx.x * 4 + (threadIdx.x >> 6);
    int lane = threadIdx.x & 63;
    float s = 0.f;
#pragma unroll
    for (int i = 0; i < 2; i++) {
        int c = lane + i * 64;
        float4 v = x4[row * (DIM / 4) + c];
        res4[row * (DIM / 4) + c] = v;
        *(ushort4*)&Xh[(size_t)row * DIM + c * 4] =
            make_ushort4(bf16rne(v.x), bf16rne(v.y), bf16rne(v.z), bf16rne(v.w));
        s += v.x * v.x + v.y * v.y + v.z * v.z + v.w * v.w;
    }
#pragma unroll
    for (int off = 32; off; off >>= 1) s += __shfl_down(s, off, 64);
    if (lane == 0) rnorm[row] = s;
}

// cast ALL quantizer codebooks to bf16 once
__global__ __launch_bounds__(256) void k_ecast(const float4* __restrict__ e4,
                                               unsigned short* __restrict__ EhAll) {
    int i = blockIdx.x * 256 + threadIdx.x;
    float4 v = e4[i];
    *(ushort4*)&EhAll[(size_t)i * 4] =
        make_ushort4(bf16rne(v.x), bf16rne(v.y), bf16rne(v.z), bf16rne(v.w));
}

// ---- single-bf16 MFMA distance GEMM + per-row top-3 partials ----
// R9-proven: 128x256 tile, 512 thr, 2 blocks/CU, XCD swizzle, branch-free
// per-lane top-3 insert (codes increase with ct -> plain `<` == tie->lower).
__global__ __launch_bounds__(512, 4) void k_gemm(
        const unsigned short* __restrict__ Xh,
        const unsigned short* __restrict__ Eh,    // this quantizer
        const float* __restrict__ enorm_q,
        float* __restrict__ pd1, int* __restrict__ pk1,
        float* __restrict__ pd2, int* __restrict__ pk2,
        float* __restrict__ pd3, int* __restrict__ nflag) {
    __shared__ __align__(16) unsigned short sXh[128 * BK];   // 16 KB
    __shared__ __align__(16) unsigned short sEh[256 * BK];   // 32 KB
    __shared__ float sD1[2][128]; __shared__ int sK1[2][128];
    __shared__ float sD2[2][128]; __shared__ int sK2[2][128];
    __shared__ float sD3[2][128];

    const int tid = threadIdx.x;
    if (blockIdx.x == 0 && tid == 0) *nflag = 0;   // reset flag list for this step
    const int l   = tid & 63;
    const int w   = tid >> 6;
    const int wm  = w >> 1;
    const int wn  = w & 1;
    // XCD-aware bijective swizzle: all 4 nt-blocks of one mt share an XCD.
    const int xcd = blockIdx.x & 7;
    const int tt  = blockIdx.x >> 3;
    const int nt  = tt & 3;
    const int mt  = ((tt >> 2) << 3) | xcd;
    const int l15 = l & 15;
    const int lq4 = l >> 4;
    const int srow = l >> 3;
    const int sgrp = (l & 7) ^ srow;

    f32x4 acc[2][8];
#pragma unroll
    for (int rt = 0; rt < 2; rt++)
#pragma unroll
        for (int ct = 0; ct < 8; ct++) acc[rt][ct] = (f32x4){0.f, 0.f, 0.f, 0.f};

    const unsigned short* gX = Xh + (size_t)(mt * 128) * DIM;
    const unsigned short* gE = Eh + (size_t)(nt * 256) * DIM;
    const int swz = l15 & 7;

    for (int c = 0; c < 8; c++) {
        __syncthreads();
#pragma unroll
        for (int i = 0; i < 2; i++) {
            int r = w * 16 + i * 8 + srow;
            GLOBAL_LOAD_LDS16(gX + (size_t)r * DIM + c * BK + sgrp * 8,
                              &sXh[(w * 16 + i * 8) * BK]);
        }
#pragma unroll
        for (int i = 0; i < 4; i++) {
            int r = w * 32 + i * 8 + srow;
            GLOBAL_LOAD_LDS16(gE + (size_t)r * DIM + c * BK + sgrp * 8,
                              &sEh[(w * 32 + i * 8) * BK]);
        }
        __syncthreads();

#pragma unroll
        for (int ks = 0; ks < 2; ks++) {
            const int g = ((ks * 4 + lq4) ^ swz) * 8;
            const int r0 = wm * 32 + l15;
            short8x a0 = *(const short8x*)&sXh[r0 * BK + g];
            short8x a1 = *(const short8x*)&sXh[(r0 + 16) * BK + g];
#pragma unroll
            for (int ct = 0; ct < 8; ct++) {
                const int br = wn * 128 + ct * 16 + l15;
                short8x b = *(const short8x*)&sEh[br * BK + g];
                acc[0][ct] = __builtin_amdgcn_mfma_f32_16x16x32_bf16(a0, b, acc[0][ct], 0, 0, 0);
                acc[1][ct] = __builtin_amdgcn_mfma_f32_16x16x32_bf16(a1, b, acc[1][ct], 0, 0, 0);
            }
        }
    }

    // epilogue: per-lane top-3 over this wave's 128 codes, per row slot.
    // Branch-free insert: codes increase with ct, so a plain `<` implements
    // the tie->lower-code rule (on tie keep old).
    float d1[2][4], d2[2][4], d3[2][4]; int k1[2][4], k2[2][4];
#pragma unroll
    for (int rt = 0; rt < 2; rt++)
#pragma unroll
        for (int r = 0; r < 4; r++) {
            d1[rt][r] = 3.4e38f; d2[rt][r] = 3.4e38f; d3[rt][r] = 3.4e38f;
            k1[rt][r] = 0; k2[rt][r] = 0;
        }

#pragma unroll
    for (int ct = 0; ct < 8; ct++) {
        int codeg = nt * 256 + wn * 128 + ct * 16 + l15;   // C/D: col = lane&15
        float en = enorm_q[codeg];
#pragma unroll
        for (int rt = 0; rt < 2; rt++)
#pragma unroll
            for (int r = 0; r < 4; r++) {
                float d = en - 2.0f * acc[rt][ct][r];
                bool b1 = d < d1[rt][r];
                bool b2 = d < d2[rt][r];
                bool b3 = d < d3[rt][r];
                d3[rt][r] = b2 ? d2[rt][r] : (b3 ? d : d3[rt][r]);
                d2[rt][r] = b1 ? d1[rt][r] : (b2 ? d : d2[rt][r]);
                k2[rt][r] = b1 ? k1[rt][r] : (b2 ? codeg : k2[rt][r]);
                d1[rt][r] = b1 ? d : d1[rt][r];
                k1[rt][r] = b1 ? codeg : k1[rt][r];
            }
    }
#pragma unroll
    for (int m = 1; m < 16; m <<= 1) {
#pragma unroll
        for (int rt = 0; rt < 2; rt++)
#pragma unroll
            for (int r = 0; r < 4; r++) {
                float o1 = __shfl_xor(d1[rt][r], m, 64);
                int   q1 = __shfl_xor(k1[rt][r], m, 64);
                float o2 = __shfl_xor(d2[rt][r], m, 64);
                int   q2 = __shfl_xor(k2[rt][r], m, 64);
                float o3 = __shfl_xor(d3[rt][r], m, 64);
                merge3(d1[rt][r], k1[rt][r], d2[rt][r], k2[rt][r], d3[rt][r],
                       o1, q1, o2, q2, o3);
            }
    }
    if (l15 == 0) {
#pragma unroll
        for (int rt = 0; rt < 2; rt++)
#pragma unroll
            for (int r = 0; r < 4; r++) {
                int rloc = wm * 32 + rt * 16 + lq4 * 4 + r;   // C/D: row = quad*4 + reg
                sD1[wn][rloc] = d1[rt][r]; sK1[wn][rloc] = k1[rt][r];
                sD2[wn][rloc] = d2[rt][r]; sK2[wn][rloc] = k2[rt][r];
                sD3[wn][rloc] = d3[rt][r];
            }
    }
    __syncthreads();
    if (tid < 128) {
        float a1 = sD1[0][tid], a2 = sD2[0][tid], a3 = sD3[0][tid];
        int   ak1 = sK1[0][tid], ak2 = sK2[0][tid];
        merge3(a1, ak1, a2, ak2, a3,
               sD1[1][tid], sK1[1][tid], sD2[1][tid], sK2[1][tid], sD3[1][tid]);
        int grow = mt * 128 + tid;
        pd1[nt * NROWS + grow] = a1; pk1[nt * NROWS + grow] = ak1;
        pd2[nt * NROWS + grow] = a2; pk2[nt * NROWS + grow] = ak2;
        pd3[nt * NROWS + grow] = a3;
    }
}

// fused combine + decision + residual update.
// v8: fast-path skip of the exact top-2 verification. The same bf16 error
// bound that justifies the d3-d1>=thr rescan filter gives: if d2-d1 >= thr
// the bf16 winner k1 IS the exact winner -> no fp32 dots, no bv stream, no
// shfl reduces for ~99% of rows. Rows with d2-d1 < thr keep the exact fp32
// top-2 comparison (unchanged code); flagged rows still go to full rescan.
__global__ __launch_bounds__(512) void k_post(
        const float* __restrict__ pd1, const int* __restrict__ pk1,
        const float* __restrict__ pd2, const int* __restrict__ pk2,
        const float* __restrict__ pd3,
        float* __restrict__ res, float* __restrict__ rnorm,
        unsigned short* __restrict__ Xh,
        const float* __restrict__ embed_q, const float* __restrict__ enorm_q,
        double* __restrict__ loss_part, float* __restrict__ out_idx,
        int* __restrict__ nflag, int* __restrict__ flag_list,
        unsigned long long* __restrict__ packed, int q) {
    __shared__ int sIdx1[16], sIdx2[16], sFlag[16], sFast[16];
    __shared__ float ls_loss[8];

    const int tid = threadIdx.x;
    const int rbase = blockIdx.x * 16;

    // Phase A: combine 4 nt top-3 partials; flag rows with d3-d1 < thr;
    // fast rows have d2-d1 >= thr (bf16 winner provably exact).
    if (tid < 16) {
        int row = rbase + tid;
        float d1 = pd1[row], d2 = pd2[row], d3 = pd3[row];
        int   k1 = pk1[row], k2 = pk2[row];
#pragma unroll
        for (int nt = 1; nt < 4; nt++) {
            merge3(d1, k1, d2, k2, d3,
                   pd1[nt * NROWS + row], pk1[nt * NROWS + row],
                   pd2[nt * NROWS + row], pk2[nt * NROWS + row],
                   pd3[nt * NROWS + row]);
        }
        sIdx1[tid] = k1; sIdx2[tid] = k2;
        float thr = FLAG_REL * sqrtf(rnorm[row]) + FLAG_ABS;
        int fl = (d3 - d1) < thr;
        sFlag[tid] = fl;
        sFast[tid] = (d2 - d1) >= thr;
        if (fl) {
            int p = atomicAdd(nflag, 1);
            flag_list[p] = row;
            packed[p] = 0xFFFFFFFFFFFFFFFFull;   // init slot for k_rare1 atomicMin
        }
    }
    __syncthreads();

    // Phase B: winner decision + update (32 thr/row)
    {
        const int rloc = tid >> 5, seg = tid & 31;
        const int row  = rbase + rloc;
        const int k1   = sIdx1[rloc], k2 = sIdx2[rloc];
        const int fl   = sFlag[rloc];
        const int fast = sFast[rloc];
        const int wave = tid >> 6, lid = tid & 63;
        const float4* r4 = (const float4*)res + (size_t)row * (DIM / 4);
        const float4* a4 = (const float4*)embed_q + (size_t)k1 * (DIM / 4);
        float4 rv[4], av[4];
#pragma unroll
        for (int u = 0; u < 4; u++) {
            rv[u] = r4[seg + 32 * u];
            av[u] = a4[seg + 32 * u];
        }
        int kw = k1;
        if (!fast) {
            const float4* b4 = (const float4*)embed_q + (size_t)k2 * (DIM / 4);
            float4 bv[4];
            float dot1 = 0.f, dot2 = 0.f;
#pragma unroll
            for (int u = 0; u < 4; u++) {
                bv[u] = b4[seg + 32 * u];
                dot1 += rv[u].x * av[u].x; dot1 += rv[u].y * av[u].y;
                dot1 += rv[u].z * av[u].z; dot1 += rv[u].w * av[u].w;
                dot2 += rv[u].x * bv[u].x; dot2 += rv[u].y * bv[u].y;
                dot2 += rv[u].z * bv[u].z; dot2 += rv[u].w * bv[u].w;
            }
#pragma unroll
            for (int m = 1; m < 32; m <<= 1) {
                dot1 += __shfl_xor(dot1, m, 64);
                dot2 += __shfl_xor(dot2, m, 64);
            }
            float rn = rnorm[row];
            float da = (rn + enorm_q[k1]) - 2.0f * dot1;
            float db = (rn + enorm_q[k2]) - 2.0f * dot2;
            bool useb = (db < da || (db == da && k2 < k1));
            if (useb) {
                kw = k2;
#pragma unroll
                for (int u = 0; u < 4; u++) av[u] = bv[u];
            }
        }

        float sl = 0.f;
        if (!fl) {
            float sr = 0.f;
#pragma unroll
            for (int u = 0; u < 4; u++) {
                float4 ev = av[u];
                // t = q - r; q_st = r + t; new_r = r - q_st  (exact op order)
                float tx = ev.x - rv[u].x, ty = ev.y - rv[u].y;
                float tz = ev.z - rv[u].z, tw = ev.w - rv[u].w;
                float qx = rv[u].x + tx, qy = rv[u].y + ty;
                float qz = rv[u].z + tz, qw = rv[u].w + tw;
                float nx = rv[u].x - qx, ny = rv[u].y - qy;
                float nz = rv[u].z - qz, nw = rv[u].w - qw;
                int col = seg + 32 * u;
                ((float4*)res)[(size_t)row * (DIM / 4) + col] =
                    make_float4(nx, ny, nz, nw);
                *(ushort4*)&Xh[(size_t)row * DIM + col * 4] =
                    make_ushort4(bf16rne(nx), bf16rne(ny), bf16rne(nz), bf16rne(nw));
                sl += tx * tx + ty * ty + tz * tz + tw * tw;
                sr += nx * nx + ny * ny + nz * nz + nw * nw;
            }
            if (seg == 0) out_idx[(size_t)row * QQ + q] = (float)kw;
            float srr = sr;
#pragma unroll
            for (int m = 1; m < 32; m <<= 1) srr += __shfl_xor(srr, m, 64);
            if (seg == 0) rnorm[row] = srr;
        }
#pragma unroll
        for (int m = 1; m < 64; m <<= 1) sl += __shfl_xor(sl, m, 64);
        if (lid == 0) ls_loss[wave] = sl;
    }
    __syncthreads();
    if (tid == 0) {
        float s = 0.f;
#pragma unroll
        for (int w = 0; w < 8; w++) s += ls_loss[w];
        double cur = (q == 0) ? 0.0 : loss_part[blockIdx.x];
        loss_part[blockIdx.x] = cur + (double)s;
    }
}

// rare rescan phase 1: block = (flag-slot stream, chunk of 32 codes).
// 8 lanes/code x 64 dims; exact fp32 dist. Full in-block reduction of the 32
// candidates (wave shfl + LDS across waves) -> ONE atomicMin per block-iter.
// Packed u64 = (order-preserving dist | code) so min == (min dist, tie -> min
// code), matching jnp.argmin exactly.
__global__ __launch_bounds__(256) void k_rare1(
        const int* __restrict__ nflag, const int* __restrict__ flag_list,
        const float* __restrict__ res, const float* __restrict__ rnorm,
        const float* __restrict__ embed_q, const float* __restrict__ enorm_q,
        unsigned long long* __restrict__ packed) {
    __shared__ unsigned long long swmin[4];
    const int nf = *nflag;
    const int tid  = threadIdx.x;
    const int c    = blockIdx.x & (RCH - 1);          // chunk within codebook
    const int fs   = blockIdx.x >> 5;                 // starting flag slot
    const int fstp = (int)(gridDim.x >> 5);           // flag-slot stride
    const int code = c * RCODES + (tid >> 3);         // this thread's code
    const int seg  = tid & 7;                         // 64-dim segment
    const int lane = tid & 63, wv = tid >> 6;
    const float* ep = embed_q + (size_t)code * DIM + seg * 64;
    const float  en = enorm_q[code];
    for (int f = fs; f < nf; f += fstp) {
        const int row = flag_list[f];
        const float* rp = res + (size_t)row * DIM + seg * 64;
        float dot = 0.f;
#pragma unroll
        for (int u = 0; u < 16; u++) {
            float4 r = *(const float4*)(rp + u * 4);
            float4 e = *(const float4*)(ep + u * 4);
            dot += r.x * e.x; dot += r.y * e.y;
            dot += r.z * e.z; dot += r.w * e.w;
        }
#pragma unroll
        for (int m = 1; m < 8; m <<= 1) dot += __shfl_xor(dot, m, 64);
        unsigned long long pk = 0xFFFFFFFFFFFFFFFFull;
        if (seg == 0) {
            float dist = (rnorm[row] + en) - 2.0f * dot;
            unsigned int u = __float_as_uint(dist);
            u = (u & 0x80000000u) ? ~u : (u | 0x80000000u);
            pk = ((unsigned long long)u << 32) | (unsigned int)code;
        }
        // wave-level min over the 8 code-holders (lanes 0,8,...,56; rest = MAX)
#pragma unroll
        for (int m = 8; m < 64; m <<= 1) {
            unsigned int hi = (unsigned int)(pk >> 32), lo = (unsigned int)pk;
            unsigned int ohi = (unsigned int)__shfl_xor((int)hi, m, 64);
            unsigned int olo = (unsigned int)__shfl_xor((int)lo, m, 64);
            unsigned long long o = ((unsigned long long)ohi << 32) | olo;
            if (o < pk) pk = o;
        }
        if (lane == 0) swmin[wv] = pk;
        __syncthreads();
        if (tid == 0) {
            unsigned long long b = swmin[0];
            if (swmin[1] < b) b = swmin[1];
            if (swmin[2] < b) b = swmin[2];
            if (swmin[3] < b) b = swmin[3];
            atomicMin(&packed[f], b);
        }
        __syncthreads();
    }
}

// rare rescan phase 2: per flagged row, unpack winner + residual/Xh/loss update.
__global__ __launch_bounds__(128) void k_rare2(
        const int* __restrict__ nflag, const int* __restrict__ flag_list,
        const unsigned long long* __restrict__ packed,
        float* __restrict__ res, float* __restrict__ rnorm,
        unsigned short* __restrict__ Xh,
        const float* __restrict__ embed_q,
        double* __restrict__ loss_rare, float* __restrict__ out_idx, int q) {
    __shared__ float ls[2], rs[2];
    const int nf = *nflag;
    const int tid = threadIdx.x;
    const int lid = tid & 63, wv = tid >> 6;
    for (int f = blockIdx.x; f < nf; f += gridDim.x) {
        const int row   = flag_list[f];
        const int kbest = (int)(packed[f] & 0xFFFFFFFFull);
        float4 rv = *(const float4*)&res[(size_t)row * DIM + tid * 4];
        float4 ev = *(const float4*)&embed_q[(size_t)kbest * DIM + tid * 4];
        float tx = ev.x - rv.x, ty = ev.y - rv.y, tz = ev.z - rv.z, tw = ev.w - rv.w;
        float qx = rv.x + tx, qy = rv.y + ty, qz = rv.z + tz, qw = rv.w + tw;
        float nx = rv.x - qx, ny = rv.y - qy, nz = rv.z - qz, nw = rv.w - qw;
        *(float4*)&res[(size_t)row * DIM + tid * 4] = make_float4(nx, ny, nz, nw);
        *(ushort4*)&Xh[(size_t)row * DIM + tid * 4] =
            make_ushort4(bf16rne(nx), bf16rne(ny), bf16rne(nz), bf16rne(nw));
        float sl = tx * tx + ty * ty + tz * tz + tw * tw;
        float sr = nx * nx + ny * ny + nz * nz + nw * nw;
#pragma unroll
        for (int m = 1; m < 64; m <<= 1) {
            sl += __shfl_xor(sl, m, 64);
            sr += __shfl_xor(sr, m, 64);
        }
        if (lid == 0) { ls[wv] = sl; rs[wv] = sr; }
        __syncthreads();
        if (tid == 0) {
            rnorm[row] = rs[0] + rs[1];
            atomicAdd(loss_rare, (double)(ls[0] + ls[1]));
            out_idx[(size_t)row * QQ + q] = (float)kbest;
        }
        __syncthreads();
    }
}

// qout = x - res_final ; block 0 reduces loss partials + rare loss
__global__ __launch_bounds__(256) void k_final(const float4* __restrict__ x4,
                                               const float4* __restrict__ res4,
                                               float4* __restrict__ out4,
                                               const double* __restrict__ loss_part,
                                               const double* __restrict__ loss_rare,
                                               float* __restrict__ out_scalar) {
    int i = blockIdx.x * 256 + threadIdx.x;
    float4 a = x4[i], b = res4[i];
    out4[i] = make_float4(a.x - b.x, a.y - b.y, a.z - b.z, a.w - b.w);
    if (blockIdx.x == 0 && threadIdx.x < 64) {
        double s = 0.0;
#pragma unroll
        for (int j = 0; j < 16; j++) s += loss_part[threadIdx.x + 64 * j];
#pragma unroll
        for (int m = 1; m < 64; m <<= 1) s += __shfl_xor(s, m, 64);
        if (threadIdx.x == 0)
            out_scalar[0] = (float)((s + *loss_rare) * 2.0 / (double)QOUT_SZ);
    }
}

extern "C" void kernel_launch(void* const* d_in, const int* in_sizes, int n_in,
                              void* d_out, int out_size, void* d_ws, size_t ws_size,
                              hipStream_t stream) {
    const float* x      = (const float*)d_in[0];   // [NROWS][DIM]
    const float* embeds = (const float*)d_in[1];   // [QQ][KK][DIM]

    char*   ws        = (char*)d_ws;
    double* loss_part = (double*)(ws + WS_LOSSP_OFF);
    double* loss_rare = (double*)(ws + WS_LOSSR_OFF);
    int*    nflag     = (int*)   (ws + WS_NFLAG_OFF);
    int*    flag_list = (int*)   (ws + WS_FLAG_OFF);
    float*  rnorm     = (float*) (ws + WS_RNORM_OFF);
    float*  enorm     = (float*) (ws + WS_ENORM_OFF);
    float*  pd1       = (float*) (ws + WS_PD1_OFF);
    int*    pk1       = (int*)   (ws + WS_PK1_OFF);
    float*  pd2       = (float*) (ws + WS_PD2_OFF);
    int*    pk2       = (int*)   (ws + WS_PK2_OFF);
    float*  pd3       = (float*) (ws + WS_PD3_OFF);
    unsigned short* EhAll = (unsigned short*)(ws + WS_EH_OFF);
    unsigned short* Xh    = (unsigned short*)(ws + WS_XH_OFF);
    float*  res       = (float*) (ws + WS_RES_OFF);
    unsigned long long* packed = (unsigned long long*)(ws + WS_PACK_OFF);

    float* out_q      = (float*)d_out;
    float* out_idx    = out_q + QOUT_SZ;
    float* out_scalar = out_q + QOUT_SZ + IDX_SZ;

    k_enorm<<<(QQ * KK) / 4, 256, 0, stream>>>((const float4*)embeds, enorm);
    k_prep <<<NROWS / 4, 256, 0, stream>>>((const float4*)x, (float4*)res, rnorm, Xh, loss_rare);
    k_ecast<<<(QQ * KK * DIM) / 4 / 256, 256, 0, stream>>>((const float4*)embeds, EhAll);

    for (int q = 0; q < QQ; q++) {
        const float* embed_q = embeds + (size_t)q * KK * DIM;
        const float* enorm_q = enorm + q * KK;
        const unsigned short* Eh_q = EhAll + (size_t)q * KK * DIM;
        k_gemm<<<512, 512, 0, stream>>>(Xh, Eh_q, enorm_q, pd1, pk1, pd2, pk2, pd3, nflag);
        k_post<<<1024, 512, 0, stream>>>(pd1, pk1, pd2, pk2, pd3, res, rnorm, Xh,
                                         embed_q, enorm_q, loss_part, out_idx,
                                         nflag, flag_list, packed, q);
        k_rare1<<<1024, 256, 0, stream>>>(nflag, flag_list, res, rnorm,
                                          embed_q, enorm_q, packed);
        k_rare2<<<128, 128, 0, stream>>>(nflag, flag_list, packed, res, rnorm, Xh,
                                         embed_q, loss_rare, out_idx, q);
    }

    k_final<<<QOUT_SZ / 4 / 256, 256, 0, stream>>>((const float4*)x, (const float4*)res,
                                                   (float4*)d_out, loss_part, loss_rare,
                                                   out_scalar);
}